// Round 7
// baseline (401.664 us; speedup 1.0000x reference)
//
#include <hip/hip_runtime.h>
#include <hip/hip_bf16.h>
#include <stdint.h>

#define N 4096

typedef __attribute__((ext_vector_type(4))) float f32x4;
typedef __attribute__((ext_vector_type(8))) short s16x8;   // 8 bf16 lanes (4 VGPRs)

__device__ inline unsigned short f2bf(float f) {
    unsigned int u = __float_as_uint(f);
    u += 0x7fffu + ((u >> 16) & 1u);        // RNE
    return (unsigned short)(u >> 16);
}
__device__ inline float bf2f(unsigned short h) {
    return __uint_as_float(((unsigned int)h) << 16);
}

// ---------------- k0a: T = w3@w2 [64][256] per graph, b_eff = w3@(w2@b1+b2)+b3 ----------------
__global__ void k0a(const float* __restrict__ w2a, const float* __restrict__ w3a,
                    const float* __restrict__ b1a, const float* __restrict__ b2a, const float* __restrict__ b3a,
                    const float* __restrict__ w2b, const float* __restrict__ w3b,
                    const float* __restrict__ b1b, const float* __restrict__ b2b, const float* __restrict__ b3b,
                    float* __restrict__ T, float* __restrict__ beff) {
    const int g  = blockIdx.x >> 5;
    const int nb = blockIdx.x & 31;
    const float* w2 = g ? w2b : w2a;   // [128][256]
    const float* w3 = g ? w3b : w3a;   // [64][128]
    const int c  = threadIdx.x;
    const int n0 = nb * 2;
    float a0 = 0.f, a1 = 0.f;
#pragma unroll 8
    for (int r = 0; r < 128; ++r) {
        float w = w2[r * 256 + c];
        a0 += w3[n0 * 128 + r] * w;            // block-uniform -> s_load
        a1 += w3[n0 * 128 + 128 + r] * w;
    }
    float* Tg = T + g * 64 * 256;
    Tg[n0 * 256 + c]       = a0;
    Tg[(n0 + 1) * 256 + c] = a1;

    if (nb == 0) {                              // bias path, parallelized (biases zero in setup; compute anyway)
        __shared__ float ps[256];
        __shared__ float u[128];
        const float* b1 = g ? b1b : b1a;
        const float* b2 = g ? b2b : b2a;
        const float* b3 = g ? b3b : b3a;
        {   // stage 1: u[r] = w2[r,:]·b1 + b2[r], split 2 ways per r
            const int r = threadIdx.x >> 1, half = threadIdx.x & 1;
            float s = 0.f;
#pragma unroll 8
            for (int cc = 0; cc < 128; ++cc) s += w2[r * 256 + half * 128 + cc] * b1[half * 128 + cc];
            ps[threadIdx.x] = s;
        }
        __syncthreads();
        if (threadIdx.x < 128)
            u[threadIdx.x] = ps[2 * threadIdx.x] + ps[2 * threadIdx.x + 1] + b2[threadIdx.x];
        __syncthreads();
        {   // stage 2: beff[n] = w3[n,:]·u + b3[n], split 4 ways per n
            const int n = threadIdx.x >> 2, qr = threadIdx.x & 3;
            float s = 0.f;
#pragma unroll
            for (int r = 0; r < 32; ++r) s += w3[n * 128 + qr * 32 + r] * u[qr * 32 + r];
            ps[threadIdx.x] = s;
        }
        __syncthreads();
        if (threadIdx.x < 64)
            beff[g * 64 + threadIdx.x] = ps[4 * threadIdx.x] + ps[4 * threadIdx.x + 1]
                                       + ps[4 * threadIdx.x + 2] + ps[4 * threadIdx.x + 3] + b3[threadIdx.x];
    }
}

// ---------------- k0b: Weff = T@w1 -> Wfrag (MFMA fragment layout, hi/lo planes) ----------------
__global__ __launch_bounds__(256) void k0b(const float* __restrict__ w1a, const float* __restrict__ w1b,
                                           const float* __restrict__ T,
                                           unsigned short* __restrict__ Wfrag) {
    const int b  = blockIdx.x;                        // ((g*16 + n4)*16 + kchunk)
    const int g = b >> 8, n4 = (b >> 4) & 15, kchunk = b & 15;
    const float* w1 = g ? w1b : w1a;                  // [256][4096]
    const int kx = kchunk * 256 + threadIdx.x;
    const float* Tg = T + (size_t)(g * 64 + n4 * 4) * 256;   // block-uniform rows -> s_load
    float acc[4] = {0.f, 0.f, 0.f, 0.f};
#pragma unroll 8
    for (int r = 0; r < 256; ++r) {
        float w = w1[(size_t)r * N + kx];
#pragma unroll
        for (int j = 0; j < 4; ++j) acc[j] += Tg[j * 256 + r] * w;
    }
    const int kc = kx >> 6, cc = (kx >> 5) & 1, q = (kx >> 3) & 3, ko = kx & 7;
#pragma unroll
    for (int j = 0; j < 4; ++j) {
        const int n = n4 * 4 + j;
        const int ng = n >> 4, l15 = n & 15;
        const int lane = q * 16 + l15;
        const unsigned short hi = f2bf(acc[j]);
        const unsigned short lo = f2bf(acc[j] - bf2f(hi));
        const size_t unit = ((((size_t)g * 64 + kc) * 4 + ng) * 2 + cc) * 2;
        Wfrag[unit * 512 + lane * 8 + ko]       = hi;
        Wfrag[(unit + 1) * 512 + lane * 8 + ko] = lo;
    }
}

// ---------------- k1: partial h = x @ Weff.T over a K-quarter; LDS-staged x, M=64 tile --------
// NEW vs r5/r6: x is staged through LDS with per-thread 128B CONTIGUOUS runs (per wave: 8 rows
// x 1KB — copy-shaped, the pattern that fixed k2 in r2), converted once to hi/lo bf16 planes in
// an XOR-swizzled tile. MFMA A-fragments come from 16B ds_reads (2-way conflict = free).
// Wave roles: 4 row-groups x 2 kc-parities per 256-col slab; all 8 waves compute every slab.
// accs_h aliases the staging LDS (phase-disjoint) -> 64KB LDS, 2 blocks/CU.
__global__ __launch_bounds__(512, 2) void k1(const float* __restrict__ x1, const float* __restrict__ x2,
                                             const unsigned short* __restrict__ Wfrag,
                                             float* __restrict__ ph) {
    const int b  = blockIdx.x;
    const int rt = b >> 2, ks = b & 3;
    const int g  = rt >> 6;
    const int rbase = (rt & 63) * 64;               // row base within graph
    const float* x = g ? x2 : x1;

    const int t = threadIdx.x;
    const int lane = t & 63, w = t >> 6;
    const int rg = w & 3, ch = w >> 2;              // row-group, kc-parity within slab
    const int q = lane >> 4, l15 = lane & 15;

    __shared__ __align__(16) unsigned short amx[2][64][256];   // 64 KB: [plane hi/lo][row][col]
    char* const amb = (char*)&amx[0][0][0];
    float (*accs_h)[4][64][4] = reinterpret_cast<float (*)[4][64][4]>(amb); // phase-disjoint reuse (16 KB)

    f32x4 acc[4];
#pragma unroll
    for (int ng = 0; ng < 4; ++ng) acc[ng] = (f32x4){0.f, 0.f, 0.f, 0.f};

    // staging role: thread t stages row srow, floats [scol, scol+32) of each 256-col slab
    const int srow = t >> 3, scol = (t & 7) * 32;
    const float* xs = x + (size_t)(rbase + srow) * N + ks * 1024 + scol;
    const int swz = (srow & 7) << 4;

    // compute-side read row
    const int rdrow = rg * 16 + l15;
    const int rswz = (rdrow & 7) << 4;

    for (int s = 0; s < 4; ++s) {
        // ---- stage slab s: 8 contiguous float4 loads per thread ----
        float4 xv4[8];
#pragma unroll
        for (int u = 0; u < 8; ++u) xv4[u] = *(const float4*)&xs[s * 256 + u * 4];
#pragma unroll
        for (int u2 = 0; u2 < 4; ++u2) {
            const float4 a = xv4[2 * u2], b2 = xv4[2 * u2 + 1];
            const float fv[8] = {a.x, a.y, a.z, a.w, b2.x, b2.y, b2.z, b2.w};
            s16x8 hi8, lo8;
#pragma unroll
            for (int j = 0; j < 8; ++j) {
                const unsigned short h = f2bf(fv[j]);
                hi8[j] = (short)h;
                lo8[j] = (short)f2bf(fv[j] - bf2f(h));
            }
            const int boff = (srow * 512 + (scol + u2 * 8) * 2) ^ swz;
            *(s16x8*)(amb + boff)         = hi8;        // hi plane
            *(s16x8*)(amb + 32768 + boff) = lo8;        // lo plane
        }
        __syncthreads();

        // ---- compute slab s: wave (rg,ch) does kc_local = ch*2+{0,1} ----
#pragma unroll
        for (int kk = 0; kk < 2; ++kk) {
            const int kcl = ch * 2 + kk;
            const int kc  = ks * 16 + s * 4 + kcl;
#pragma unroll
            for (int c = 0; c < 2; ++c) {
                const int col = kcl * 64 + c * 32 + q * 8;
                const int ro  = (rdrow * 512 + col * 2) ^ rswz;
                s16x8 ah = *(const s16x8*)(amb + ro);
                s16x8 al = *(const s16x8*)(amb + 32768 + ro);
                s16x8 bh[4], bl[4];
#pragma unroll
                for (int ng = 0; ng < 4; ++ng) {
                    const size_t unit = ((((size_t)g * 64 + kc) * 4 + ng) * 2 + c) * 2;
                    bh[ng] = *(const s16x8*)&Wfrag[unit * 512 + lane * 8];
                    bl[ng] = *(const s16x8*)&Wfrag[(unit + 1) * 512 + lane * 8];
                }
#pragma unroll
                for (int ng = 0; ng < 4; ++ng) {
                    acc[ng] = __builtin_amdgcn_mfma_f32_16x16x32_bf16(al, bh[ng], acc[ng], 0, 0, 0);
                    acc[ng] = __builtin_amdgcn_mfma_f32_16x16x32_bf16(ah, bl[ng], acc[ng], 0, 0, 0);
                    acc[ng] = __builtin_amdgcn_mfma_f32_16x16x32_bf16(ah, bh[ng], acc[ng], 0, 0, 0);
                }
            }
        }
        __syncthreads();                        // before next slab overwrites amx
    }

    // ---- pairwise reduction over ch (accs_h aliases amx; last sync above fences it) ----
    if (ch == 1) {
#pragma unroll
        for (int ng = 0; ng < 4; ++ng)
#pragma unroll
            for (int r = 0; r < 4; ++r) accs_h[rg][ng][lane][r] = acc[ng][r];
    }
    __syncthreads();
    if (ch == 0) {
        // lane (q,l15), reg r of acc[ng] holds h-partial[row = rg*16 + q*4 + r][n = ng*16 + l15]
        const int girow = g * 4096 + rbase + rg * 16 + q * 4;
#pragma unroll
        for (int ng = 0; ng < 4; ++ng) {
            const int n = ng * 16 + l15;
#pragma unroll
            for (int r = 0; r < 4; ++r) {
                float s = acc[ng][r] + accs_h[rg][ng][lane][r];
                ph[((size_t)ks * 8192 + girow + r) * 64 + n] = s;
            }
        }
    }
}

// ---------------- k1b: reduce 4 K-quarter partials, +bias, relu, emit hf + hfrag --------------
__global__ __launch_bounds__(256) void k1b(const float* __restrict__ ph, const float* __restrict__ beff,
                                           float* __restrict__ hf, unsigned short* __restrict__ hfrag) {
    const int b = blockIdx.x;
    const int g = b & 1;
    const int i0 = (b >> 1) * 16;
    const int t = threadIdx.x;
    const int il = t >> 4, nq = t & 15;
    const int gi = g * 4096 + i0 + il;

    __shared__ unsigned short htile[64][16];        // [n][ilocal]

    f32x4 s = (f32x4){0.f, 0.f, 0.f, 0.f};
#pragma unroll
    for (int ks = 0; ks < 4; ++ks)
        s += *(const f32x4*)&ph[((size_t)ks * 8192 + gi) * 64 + nq * 4];
    f32x4 o;
#pragma unroll
    for (int j = 0; j < 4; ++j) {
        const int n = nq * 4 + j;
        float v = fmaxf(s[j] + beff[g * 64 + n], 0.f);
        o[j] = v;
        htile[n][il] = f2bf(v);
    }
    *(f32x4*)&hf[(size_t)gi * 64 + nq * 4] = o;
    __syncthreads();

    if (t < 128) {                                  // emit hfrag (identical layout to old k1)
        const int ng2 = t >> 5, jh = (t >> 4) & 1, l = t & 15;
        uint4 v = *(const uint4*)&htile[ng2 * 16 + l][jh * 8];
        const int jc = i0 >> 6, c = (i0 >> 5) & 1, q0 = (i0 >> 3) & 3;
        const size_t unit = (((size_t)g * 4 + ng2) * 64 + jc) * 2 + c;
        *(uint4*)&hfrag[unit * 512 + (size_t)(q0 + jh) * 128 + l * 8] = v;
    }
}

// ---------------- k2: staged-contiguous masked aggregation, 4-way K-split (r5 version) -------
// Reverted to the best-measured r5 structure (67 us): depth-1 register staging + __syncthreads
// per slab. r6's deeper pipeline + raw-barrier variant regressed (FETCH +18%, dur +7%).
__global__ __launch_bounds__(512, 2) void k2(const int* __restrict__ adj1, const int* __restrict__ adj2,
                                             const float* __restrict__ alpha,
                                             const unsigned short* __restrict__ hfrag,
                                             float* __restrict__ pagg, float* __restrict__ pdeg) {
    const int b  = blockIdx.x;
    const int ks = (b >> 1) & 3;
    const int i0 = ((((b >> 3) << 1) | (b & 1))) << 4;
    const int t = threadIdx.x;
    const int lane = t & 63, kg = t >> 6;           // 8 waves; wave kg owns 32-col k-tile per slab
    const int q = lane >> 4, l15 = lane & 15;

    __shared__ __align__(16) unsigned short am[2][2][16][256];  // 32 KB [buf][g][row][col], XOR-swizzled
    __shared__ float degp[2][16][32];                           // 4 KB  [g][row][colgroup]
    float (*accs)[4][64][4] = reinterpret_cast<float (*)[4][64][4]>(&am[0][0][0][0]); // phase-disjoint reuse

    f32x4 acc1[4], acc2[4];
#pragma unroll
    for (int ng = 0; ng < 4; ++ng) {
        acc1[ng] = (f32x4){0.f, 0.f, 0.f, 0.f};
        acc2[ng] = (f32x4){0.f, 0.f, 0.f, 0.f};
    }
    int deg1 = 0, deg2 = 0;

    // staging role: thread t loads row srow, cols scg*8..+8 of each 256-col slab (1KB runs/wave)
    const int srow = t >> 5, scg = t & 31;
    const size_t sbase = (size_t)(i0 + srow) * N + (size_t)ks * 1024 + (size_t)scg * 8;
    char* const amb = (char*)&am[0][0][0][0];
    const int swoff = (srow * 512 + scg * 16) ^ ((srow & 7) << 4);           // write: 16B chunk, swizzled
    const int rdoff = (l15 * 512 + kg * 64 + q * 16) ^ ((l15 & 7) << 4);     // read: same swizzle

    float4 sa0, sa1; int4 sj10, sj11, sj20, sj21;

#define K2_ISSUE(S) do { \
        const float* ap = alpha + sbase + (S) * 256; \
        sa0 = *(const float4*)ap; sa1 = *(const float4*)(ap + 4); \
        const int* p1 = adj1 + sbase + (S) * 256; \
        sj10 = *(const int4*)p1; sj11 = *(const int4*)(p1 + 4); \
        const int* p2 = adj2 + sbase + (S) * 256; \
        sj20 = *(const int4*)p2; sj21 = *(const int4*)(p2 + 4); \
    } while (0)

#define K2_CONVSTORE(BUF) do { \
        float av[8] = {sa0.x, sa0.y, sa0.z, sa0.w, sa1.x, sa1.y, sa1.z, sa1.w}; \
        int m1[8] = {sj10.x == 1, sj10.y == 1, sj10.z == 1, sj10.w == 1, \
                     sj11.x == 1, sj11.y == 1, sj11.z == 1, sj11.w == 1}; \
        int m2[8] = {sj20.x == 1, sj20.y == 1, sj20.z == 1, sj20.w == 1, \
                     sj21.x == 1, sj21.y == 1, sj21.z == 1, sj21.w == 1}; \
        s16x8 w1v, w2v; \
        _Pragma("unroll") \
        for (int j = 0; j < 8; ++j) { \
            unsigned short bv = f2bf(av[j]); \
            w1v[j] = m1[j] ? (short)bv : (short)0; \
            w2v[j] = m2[j] ? (short)bv : (short)0; \
            deg1 += m1[j]; deg2 += m2[j]; \
        } \
        *(s16x8*)(amb + (BUF) * 16384 + swoff) = w1v; \
        *(s16x8*)(amb + (BUF) * 16384 + 8192 + swoff) = w2v; \
    } while (0)

#define K2_COMPUTE(S) do { \
        const int jc = ks * 16 + (S) * 4 + (kg >> 1), cph = kg & 1; \
        s16x8 ha1[4], ha2[4]; \
        _Pragma("unroll") \
        for (int ng = 0; ng < 4; ++ng) { \
            const size_t u1 = (((size_t)ng) * 64 + jc) * 2 + cph; \
            const size_t u2 = (((size_t)(4 + ng)) * 64 + jc) * 2 + cph; \
            ha1[ng] = *(const s16x8*)&hfrag[u1 * 512 + lane * 8]; \
            ha2[ng] = *(const s16x8*)&hfrag[u2 * 512 + lane * 8]; \
        } \
        s16x8 bfa = *(const s16x8*)(amb + ((S) & 1) * 16384 + rdoff); \
        s16x8 bfb = *(const s16x8*)(amb + ((S) & 1) * 16384 + 8192 + rdoff); \
        _Pragma("unroll") \
        for (int ng = 0; ng < 4; ++ng) { \
            acc1[ng] = __builtin_amdgcn_mfma_f32_16x16x32_bf16(ha1[ng], bfa, acc1[ng], 0, 0, 0); \
            acc2[ng] = __builtin_amdgcn_mfma_f32_16x16x32_bf16(ha2[ng], bfb, acc2[ng], 0, 0, 0); \
        } \
    } while (0)

    K2_ISSUE(0);
    K2_CONVSTORE(0);
    __syncthreads();
#pragma unroll
    for (int s = 0; s < 4; ++s) {
        if (s < 3) K2_ISSUE(s + 1);          // issue next slab's HBM loads early (T14 split)
        K2_COMPUTE(s);                        // ds_read frags + hfrag(L2) + 8 MFMA
        if (s < 3) K2_CONVSTORE((s + 1) & 1); // wait own loads, convert, swizzled ds_write
        __syncthreads();
    }

    // ---- epilogue (identical reduction/layout to the passing r1 version) ----
    degp[0][srow][scg] = (float)deg1;
    degp[1][srow][scg] = (float)deg2;
#pragma unroll
    for (int ng = 0; ng < 4; ++ng)
#pragma unroll
        for (int r = 0; r < 4; ++r) accs[kg][ng][lane][r] = acc1[ng][r];
    __syncthreads();
    if (t < 32) {                                   // deg partial for this ks
        const int gg = t >> 4, row = t & 15;
        float s = 0.f;
#pragma unroll
        for (int c2 = 0; c2 < 32; ++c2) s += degp[gg][row][c2];
        pdeg[(size_t)(gg * 4 + ks) * 4096 + i0 + row] = s;
    }

    {   // graph 1 partial: lane holds (n = ng*16+q*4+r, i = i0+l15)
        const int ng = kg & 3, rh = kg >> 2;
        const int i = i0 + l15;
#pragma unroll
        for (int rr = 0; rr < 2; ++rr) {
            const int r = rh * 2 + rr;
            float s = 0.f;
#pragma unroll
            for (int k8 = 0; k8 < 8; ++k8) s += accs[k8][ng][lane][r];
            const int n = ng * 16 + q * 4 + r;
            pagg[(((size_t)ks * 4096 + i) << 6) + n] = s;
        }
    }
    __syncthreads();                                // done reading accs (graph1)
#pragma unroll
    for (int ng = 0; ng < 4; ++ng)
#pragma unroll
        for (int r = 0; r < 4; ++r) accs[kg][ng][lane][r] = acc2[ng][r];
    __syncthreads();
    {   // graph 2 partial
        const int ng = kg & 3, rh = kg >> 2;
        const int i = i0 + l15;
#pragma unroll
        for (int rr = 0; rr < 2; ++rr) {
            const int r = rh * 2 + rr;
            float s = 0.f;
#pragma unroll
            for (int k8 = 0; k8 < 8; ++k8) s += accs[k8][ng][lane][r];
            const int n = ng * 16 + q * 4 + r;
            pagg[(((size_t)(4 + ks) * 4096 + i) << 6) + n] = s;
        }
    }
#undef K2_ISSUE
#undef K2_CONVSTORE
#undef K2_COMPUTE
}

// ---------------- k2b: reduce 4 K-partials, scale by W00/deg, residual, zero-mask -------------
__global__ __launch_bounds__(256) void k2b(const float* __restrict__ pagg, const float* __restrict__ pdeg,
                                           const float* __restrict__ hf, const float* __restrict__ Wp,
                                           float* __restrict__ outv) {
    const int idx = blockIdx.x * 256 + threadIdx.x;  // 0..131071 (quads of n)
    const int gi  = idx >> 4;                        // 0..8191 (g*4096 + i)
    const int nq  = idx & 15;
    const int g   = gi >> 12, i = gi & 4095;
    const float W00 = Wp[0];

    float dg = 0.f;
#pragma unroll
    for (int ks = 0; ks < 4; ++ks) dg += pdeg[(size_t)(g * 4 + ks) * 4096 + i];

    f32x4 s = (f32x4){0.f, 0.f, 0.f, 0.f};
#pragma unroll
    for (int ks = 0; ks < 4; ++ks) {
        const f32x4 p = *(const f32x4*)&pagg[(((size_t)(g * 4 + ks) * 4096 + i) << 6) + nq * 4];
        s += p;
    }
    const f32x4 hv = *(const f32x4*)&hf[((size_t)gi << 6) + nq * 4];
    const float dmax = fmaxf(dg, 1.f);
    f32x4 o;
#pragma unroll
    for (int j = 0; j < 4; ++j)
        o[j] = (dg != 0.f) ? (s[j] * W00 / dmax + hv[j]) : 0.f;
    *(f32x4*)&outv[((size_t)gi << 6) + nq * 4] = o;
}

// ---------------- k3a/k3b: out = feat @ clf_w.T + clf_b (two-stage deterministic reduction) ----------------
__global__ __launch_bounds__(256) void k3a(const float* __restrict__ feat, const float* __restrict__ clfw,
                                           float* __restrict__ part) {
    const int t = threadIdx.x;
    const size_t idx = (size_t)blockIdx.x * 2048 + (size_t)t * 8;
    float4 a0 = *(const float4*)&feat[idx];
    float4 a1 = *(const float4*)&feat[idx + 4];
    float4 c0 = *(const float4*)&clfw[idx];
    float4 c1 = *(const float4*)&clfw[idx + 4];
    float4 d0 = *(const float4*)&clfw[524288 + idx];
    float4 d1 = *(const float4*)&clfw[524288 + idx + 4];
    float s0 = a0.x * c0.x + a0.y * c0.y + a0.z * c0.z + a0.w * c0.w
             + a1.x * c1.x + a1.y * c1.y + a1.z * c1.z + a1.w * c1.w;
    float s1 = a0.x * d0.x + a0.y * d0.y + a0.z * d0.z + a0.w * d0.w
             + a1.x * d1.x + a1.y * d1.y + a1.z * d1.z + a1.w * d1.w;
    __shared__ float r0[256], r1[256];
    r0[t] = s0; r1[t] = s1;
    __syncthreads();
    for (int s = 128; s > 0; s >>= 1) {
        if (t < s) { r0[t] += r0[t + s]; r1[t] += r1[t + s]; }
        __syncthreads();
    }
    if (t == 0) { part[blockIdx.x * 2] = r0[0]; part[blockIdx.x * 2 + 1] = r1[0]; }
}

__global__ void k3b(const float* __restrict__ part, const float* __restrict__ clfb,
                    float* __restrict__ outp) {
    const int t = threadIdx.x;
    __shared__ float r0[256], r1[256];
    r0[t] = part[t * 2]; r1[t] = part[t * 2 + 1];
    __syncthreads();
    for (int s = 128; s > 0; s >>= 1) {
        if (t < s) { r0[t] += r0[t + s]; r1[t] += r1[t + s]; }
        __syncthreads();
    }
    if (t == 0) { outp[0] = r0[0] + clfb[0]; outp[1] = r1[0] + clfb[1]; }
}

extern "C" void kernel_launch(void* const* d_in, const int* in_sizes, int n_in,
                              void* d_out, int out_size, void* d_ws, size_t ws_size,
                              hipStream_t stream) {
    const float* x1   = (const float*)d_in[0];
    const float* x2   = (const float*)d_in[1];
    const int*   adj1 = (const int*)d_in[2];
    const int*   adj2 = (const int*)d_in[3];
    const float* e1w1 = (const float*)d_in[4];
    const float* e1b1 = (const float*)d_in[5];
    const float* e1w2 = (const float*)d_in[6];
    const float* e1b2 = (const float*)d_in[7];
    const float* e1w3 = (const float*)d_in[8];
    const float* e1b3 = (const float*)d_in[9];
    const float* e2w1 = (const float*)d_in[10];
    const float* e2b1 = (const float*)d_in[11];
    const float* e2w2 = (const float*)d_in[12];
    const float* e2b2 = (const float*)d_in[13];
    const float* e2w3 = (const float*)d_in[14];
    const float* e2b3 = (const float*)d_in[15];
    const float* Wp   = (const float*)d_in[16];
    const float* alph = (const float*)d_in[17];
    const float* clfw = (const float*)d_in[18];
    const float* clfb = (const float*)d_in[19];

    char* wsb = (char*)d_ws;
    // Wfrag (2 MB) lives through k1; newv (2 MB) aliases it from k2b on.
    // ph (8 MB, k1 partials) aliases the pagg region: k1b consumes ph before k2 writes pagg.
    unsigned short* Wfrag = (unsigned short*)(wsb);                      // 2 MB
    float* newv = (float*)(wsb);                                         // 2 MB (aliases Wfrag)
    unsigned short* hfrag = (unsigned short*)(wsb + (2u << 20));         // 1 MB
    float* hf   = (float*)(wsb + (3u << 20));                            // 2 MB
    float* T    = (float*)(wsb + (5u << 20));                            // 128 KB
    float* beff = (float*)(wsb + (5u << 20) + (1u << 17));               // 512 B
    float* part = (float*)(wsb + (5u << 20) + (1u << 17) + 4096);        // 2 KB
    float* pagg = (float*)(wsb + (6u << 20));                            // 8 MB [2][4][4096][64]
    float* ph   = (float*)(wsb + (6u << 20));                            // 8 MB [4][8192][64] (aliases pagg)
    float* pdeg = (float*)(wsb + (14u << 20));                           // 128 KB [2][4][4096]

    hipLaunchKernelGGL(k0a, dim3(64), dim3(256), 0, stream,
                       e1w2, e1w3, e1b1, e1b2, e1b3, e2w2, e2w3, e2b1, e2b2, e2b3, T, beff);
    hipLaunchKernelGGL(k0b, dim3(512), dim3(256), 0, stream, e1w1, e2w1, T, Wfrag);
    hipLaunchKernelGGL(k1, dim3(512), dim3(512), 0, stream, x1, x2, Wfrag, ph);
    hipLaunchKernelGGL(k1b, dim3(512), dim3(256), 0, stream, ph, beff, hf, hfrag);
    hipLaunchKernelGGL(k2, dim3(1024), dim3(512), 0, stream, adj1, adj2, alph, hfrag, pagg, pdeg);
    hipLaunchKernelGGL(k2b, dim3(512), dim3(256), 0, stream, pagg, pdeg, hf, Wp, newv);
    hipLaunchKernelGGL(k3a, dim3(256), dim3(256), 0, stream, newv, clfw, part);
    hipLaunchKernelGGL(k3b, dim3(1), dim3(256), 0, stream, part, clfb, (float*)d_out);
}

// Round 8
// 388.902 us; speedup vs baseline: 1.0328x; 1.0328x over previous
//
#include <hip/hip_runtime.h>
#include <hip/hip_bf16.h>
#include <stdint.h>

#define N 4096

typedef __attribute__((ext_vector_type(4))) float f32x4;
typedef __attribute__((ext_vector_type(8))) short s16x8;   // 8 bf16 lanes (4 VGPRs)

__device__ inline unsigned short f2bf(float f) {
    unsigned int u = __float_as_uint(f);
    u += 0x7fffu + ((u >> 16) & 1u);        // RNE
    return (unsigned short)(u >> 16);
}
__device__ inline float bf2f(unsigned short h) {
    return __uint_as_float(((unsigned int)h) << 16);
}

// ---------------- k0a: T = w3@w2 [64][256] per graph, b_eff = w3@(w2@b1+b2)+b3 ----------------
__global__ void k0a(const float* __restrict__ w2a, const float* __restrict__ w3a,
                    const float* __restrict__ b1a, const float* __restrict__ b2a, const float* __restrict__ b3a,
                    const float* __restrict__ w2b, const float* __restrict__ w3b,
                    const float* __restrict__ b1b, const float* __restrict__ b2b, const float* __restrict__ b3b,
                    float* __restrict__ T, float* __restrict__ beff) {
    const int g  = blockIdx.x >> 5;
    const int nb = blockIdx.x & 31;
    const float* w2 = g ? w2b : w2a;   // [128][256]
    const float* w3 = g ? w3b : w3a;   // [64][128]
    const int c  = threadIdx.x;
    const int n0 = nb * 2;
    float a0 = 0.f, a1 = 0.f;
#pragma unroll 8
    for (int r = 0; r < 128; ++r) {
        float w = w2[r * 256 + c];
        a0 += w3[n0 * 128 + r] * w;            // block-uniform -> s_load
        a1 += w3[n0 * 128 + 128 + r] * w;
    }
    float* Tg = T + g * 64 * 256;
    Tg[n0 * 256 + c]       = a0;
    Tg[(n0 + 1) * 256 + c] = a1;

    if (nb == 0) {                              // bias path, parallelized (biases zero in setup; compute anyway)
        __shared__ float ps[256];
        __shared__ float u[128];
        const float* b1 = g ? b1b : b1a;
        const float* b2 = g ? b2b : b2a;
        const float* b3 = g ? b3b : b3a;
        {   // stage 1: u[r] = w2[r,:]·b1 + b2[r], split 2 ways per r
            const int r = threadIdx.x >> 1, half = threadIdx.x & 1;
            float s = 0.f;
#pragma unroll 8
            for (int cc = 0; cc < 128; ++cc) s += w2[r * 256 + half * 128 + cc] * b1[half * 128 + cc];
            ps[threadIdx.x] = s;
        }
        __syncthreads();
        if (threadIdx.x < 128)
            u[threadIdx.x] = ps[2 * threadIdx.x] + ps[2 * threadIdx.x + 1] + b2[threadIdx.x];
        __syncthreads();
        {   // stage 2: beff[n] = w3[n,:]·u + b3[n], split 4 ways per n
            const int n = threadIdx.x >> 2, qr = threadIdx.x & 3;
            float s = 0.f;
#pragma unroll
            for (int r = 0; r < 32; ++r) s += w3[n * 128 + qr * 32 + r] * u[qr * 32 + r];
            ps[threadIdx.x] = s;
        }
        __syncthreads();
        if (threadIdx.x < 64)
            beff[g * 64 + threadIdx.x] = ps[4 * threadIdx.x] + ps[4 * threadIdx.x + 1]
                                       + ps[4 * threadIdx.x + 2] + ps[4 * threadIdx.x + 3] + b3[threadIdx.x];
    }
}

// ---------------- k0b: Weff = T@w1 -> Wfrag (MFMA fragment layout, hi/lo planes) ----------------
__global__ __launch_bounds__(256) void k0b(const float* __restrict__ w1a, const float* __restrict__ w1b,
                                           const float* __restrict__ T,
                                           unsigned short* __restrict__ Wfrag) {
    const int b  = blockIdx.x;                        // ((g*16 + n4)*16 + kchunk)
    const int g = b >> 8, n4 = (b >> 4) & 15, kchunk = b & 15;
    const float* w1 = g ? w1b : w1a;                  // [256][4096]
    const int kx = kchunk * 256 + threadIdx.x;
    const float* Tg = T + (size_t)(g * 64 + n4 * 4) * 256;   // block-uniform rows -> s_load
    float acc[4] = {0.f, 0.f, 0.f, 0.f};
#pragma unroll 8
    for (int r = 0; r < 256; ++r) {
        float w = w1[(size_t)r * N + kx];
#pragma unroll
        for (int j = 0; j < 4; ++j) acc[j] += Tg[j * 256 + r] * w;
    }
    const int kc = kx >> 6, cc = (kx >> 5) & 1, q = (kx >> 3) & 3, ko = kx & 7;
#pragma unroll
    for (int j = 0; j < 4; ++j) {
        const int n = n4 * 4 + j;
        const int ng = n >> 4, l15 = n & 15;
        const int lane = q * 16 + l15;
        const unsigned short hi = f2bf(acc[j]);
        const unsigned short lo = f2bf(acc[j] - bf2f(hi));
        const size_t unit = ((((size_t)g * 64 + kc) * 4 + ng) * 2 + cc) * 2;
        Wfrag[unit * 512 + lane * 8 + ko]       = hi;
        Wfrag[(unit + 1) * 512 + lane * 8 + ko] = lo;
    }
}

// ---------------- k1: partial h = x @ Weff.T over a K-quarter; M=64 tile, 4-way K-split -------
// r6 version (best measured ~58-62us): direct x loads + sched_barrier(0)-PINNED 1-deep
// x-prefetch. Wfrag loads stay load-use (L1/L2-hot). r7's LDS staging regressed (occupancy
// halved, 3.7M bank conflicts) and is reverted.
__global__ __launch_bounds__(512, 2) void k1(const float* __restrict__ x1, const float* __restrict__ x2,
                                             const unsigned short* __restrict__ Wfrag,
                                             float* __restrict__ ph) {
    const int b  = blockIdx.x;
    const int rt = b >> 2, ks = b & 3;
    const int g  = rt >> 6;
    const int rbase = (rt & 63) * 64;               // row base within graph
    const float* x = g ? x2 : x1;

    const int t = threadIdx.x;
    const int lane = t & 63, w = t >> 6;
    const int rg = w & 3, kh = w >> 2;              // row-group, K-half
    const int q = lane >> 4, l15 = lane & 15;

    __shared__ float accs_h[4][4][64][4];           // 16 KB: kh=1 partials

    f32x4 acc[4];
#pragma unroll
    for (int ng = 0; ng < 4; ++ng) acc[ng] = (f32x4){0.f, 0.f, 0.f, 0.f};

    const float* xrow = x + (size_t)(rbase + rg * 16 + l15) * N;
    const int kcbase = ks * 16 + kh * 8;            // 8 kc units (512 cols) per wave

    float4 pa0, pa1, ra0, ra1;

#define K1_LOADX(A0, A1, IT) do { \
        const int kc_ = kcbase + ((IT) >> 1), c_ = (IT) & 1; \
        const int ka_ = kc_ * 64 + c_ * 32 + q * 8; \
        A0 = *(const float4*)&xrow[ka_]; \
        A1 = *(const float4*)&xrow[ka_ + 4]; \
    } while (0)

#define K1_STEP(A0, A1, IT) do { \
        const int kc_ = kcbase + ((IT) >> 1), c_ = (IT) & 1; \
        s16x8 bh[4], bl[4]; \
        _Pragma("unroll") \
        for (int ng = 0; ng < 4; ++ng) { \
            const size_t unit = ((((size_t)g * 64 + kc_) * 4 + ng) * 2 + c_) * 2; \
            bh[ng] = *(const s16x8*)&Wfrag[unit * 512 + lane * 8]; \
            bl[ng] = *(const s16x8*)&Wfrag[(unit + 1) * 512 + lane * 8]; \
        } \
        float xv[8] = {A0.x, A0.y, A0.z, A0.w, A1.x, A1.y, A1.z, A1.w}; \
        s16x8 ah, al; \
        _Pragma("unroll") \
        for (int j = 0; j < 8; ++j) { \
            unsigned short hh = f2bf(xv[j]); \
            ah[j] = (short)hh; \
            al[j] = (short)f2bf(xv[j] - bf2f(hh)); \
        } \
        _Pragma("unroll") \
        for (int ng = 0; ng < 4; ++ng) { \
            acc[ng] = __builtin_amdgcn_mfma_f32_16x16x32_bf16(al, bh[ng], acc[ng], 0, 0, 0); \
            acc[ng] = __builtin_amdgcn_mfma_f32_16x16x32_bf16(ah, bl[ng], acc[ng], 0, 0, 0); \
            acc[ng] = __builtin_amdgcn_mfma_f32_16x16x32_bf16(ah, bh[ng], acc[ng], 0, 0, 0); \
        } \
    } while (0)

    K1_LOADX(pa0, pa1, 0);
    __builtin_amdgcn_sched_barrier(0);
#pragma unroll
    for (int it2 = 0; it2 < 8; ++it2) {
        K1_LOADX(ra0, ra1, 2 * it2 + 1);            // issue next x pair (HBM) ...
        __builtin_amdgcn_sched_barrier(0);          // ... and PIN it above the compute
        K1_STEP(pa0, pa1, 2 * it2);
        if (it2 < 7) {
            K1_LOADX(pa0, pa1, 2 * it2 + 2);
            __builtin_amdgcn_sched_barrier(0);
        }
        K1_STEP(ra0, ra1, 2 * it2 + 1);
    }
#undef K1_LOADX
#undef K1_STEP

    if (kh == 1) {
#pragma unroll
        for (int ng = 0; ng < 4; ++ng)
#pragma unroll
            for (int r = 0; r < 4; ++r) accs_h[rg][ng][lane][r] = acc[ng][r];
    }
    __syncthreads();
    if (kh == 0) {
        // lane (q,l15), reg r of acc[ng] holds h-partial[row = rg*16 + q*4 + r][n = ng*16 + l15]
        const int girow = g * 4096 + rbase + rg * 16 + q * 4;
#pragma unroll
        for (int ng = 0; ng < 4; ++ng) {
            const int n = ng * 16 + l15;
#pragma unroll
            for (int r = 0; r < 4; ++r) {
                float s = acc[ng][r] + accs_h[rg][ng][lane][r];
                ph[((size_t)ks * 8192 + girow + r) * 64 + n] = s;
            }
        }
    }
}

// ---------------- k1b: reduce 4 K-quarter partials, +bias, relu, emit hf + hfrag --------------
__global__ __launch_bounds__(256) void k1b(const float* __restrict__ ph, const float* __restrict__ beff,
                                           float* __restrict__ hf, unsigned short* __restrict__ hfrag) {
    const int b = blockIdx.x;
    const int g = b & 1;
    const int i0 = (b >> 1) * 16;
    const int t = threadIdx.x;
    const int il = t >> 4, nq = t & 15;
    const int gi = g * 4096 + i0 + il;

    __shared__ unsigned short htile[64][16];        // [n][ilocal]

    f32x4 s = (f32x4){0.f, 0.f, 0.f, 0.f};
#pragma unroll
    for (int ks = 0; ks < 4; ++ks)
        s += *(const f32x4*)&ph[((size_t)ks * 8192 + gi) * 64 + nq * 4];
    f32x4 o;
#pragma unroll
    for (int j = 0; j < 4; ++j) {
        const int n = nq * 4 + j;
        float v = fmaxf(s[j] + beff[g * 64 + n], 0.f);
        o[j] = v;
        htile[n][il] = f2bf(v);
    }
    *(f32x4*)&hf[(size_t)gi * 64 + nq * 4] = o;
    __syncthreads();

    if (t < 128) {                                  // emit hfrag (identical layout to old k1)
        const int ng2 = t >> 5, jh = (t >> 4) & 1, l = t & 15;
        uint4 v = *(const uint4*)&htile[ng2 * 16 + l][jh * 8];
        const int jc = i0 >> 6, c = (i0 >> 5) & 1, q0 = (i0 >> 3) & 3;
        const size_t unit = (((size_t)g * 4 + ng2) * 64 + jc) * 2 + c;
        *(uint4*)&hfrag[unit * 512 + (size_t)(q0 + jh) * 128 + l * 8] = v;
    }
}

// ---------------- k2: staged-contiguous masked aggregation, 4-way K-split (r5 version) -------
__global__ __launch_bounds__(512, 2) void k2(const int* __restrict__ adj1, const int* __restrict__ adj2,
                                             const float* __restrict__ alpha,
                                             const unsigned short* __restrict__ hfrag,
                                             float* __restrict__ pagg, float* __restrict__ pdeg) {
    const int b  = blockIdx.x;
    const int ks = (b >> 1) & 3;
    const int i0 = ((((b >> 3) << 1) | (b & 1))) << 4;
    const int t = threadIdx.x;
    const int lane = t & 63, kg = t >> 6;           // 8 waves; wave kg owns 32-col k-tile per slab
    const int q = lane >> 4, l15 = lane & 15;

    __shared__ __align__(16) unsigned short am[2][2][16][256];  // 32 KB [buf][g][row][col], XOR-swizzled
    __shared__ float degp[2][16][32];                           // 4 KB  [g][row][colgroup]
    float (*accs)[4][64][4] = reinterpret_cast<float (*)[4][64][4]>(&am[0][0][0][0]); // phase-disjoint reuse

    f32x4 acc1[4], acc2[4];
#pragma unroll
    for (int ng = 0; ng < 4; ++ng) {
        acc1[ng] = (f32x4){0.f, 0.f, 0.f, 0.f};
        acc2[ng] = (f32x4){0.f, 0.f, 0.f, 0.f};
    }
    int deg1 = 0, deg2 = 0;

    // staging role: thread t loads row srow, cols scg*8..+8 of each 256-col slab (1KB runs/wave)
    const int srow = t >> 5, scg = t & 31;
    const size_t sbase = (size_t)(i0 + srow) * N + (size_t)ks * 1024 + (size_t)scg * 8;
    char* const amb = (char*)&am[0][0][0][0];
    const int swoff = (srow * 512 + scg * 16) ^ ((srow & 7) << 4);           // write: 16B chunk, swizzled
    const int rdoff = (l15 * 512 + kg * 64 + q * 16) ^ ((l15 & 7) << 4);     // read: same swizzle

    float4 sa0, sa1; int4 sj10, sj11, sj20, sj21;

#define K2_ISSUE(S) do { \
        const float* ap = alpha + sbase + (S) * 256; \
        sa0 = *(const float4*)ap; sa1 = *(const float4*)(ap + 4); \
        const int* p1 = adj1 + sbase + (S) * 256; \
        sj10 = *(const int4*)p1; sj11 = *(const int4*)(p1 + 4); \
        const int* p2 = adj2 + sbase + (S) * 256; \
        sj20 = *(const int4*)p2; sj21 = *(const int4*)(p2 + 4); \
    } while (0)

#define K2_CONVSTORE(BUF) do { \
        float av[8] = {sa0.x, sa0.y, sa0.z, sa0.w, sa1.x, sa1.y, sa1.z, sa1.w}; \
        int m1[8] = {sj10.x == 1, sj10.y == 1, sj10.z == 1, sj10.w == 1, \
                     sj11.x == 1, sj11.y == 1, sj11.z == 1, sj11.w == 1}; \
        int m2[8] = {sj20.x == 1, sj20.y == 1, sj20.z == 1, sj20.w == 1, \
                     sj21.x == 1, sj21.y == 1, sj21.z == 1, sj21.w == 1}; \
        s16x8 w1v, w2v; \
        _Pragma("unroll") \
        for (int j = 0; j < 8; ++j) { \
            unsigned short bv = f2bf(av[j]); \
            w1v[j] = m1[j] ? (short)bv : (short)0; \
            w2v[j] = m2[j] ? (short)bv : (short)0; \
            deg1 += m1[j]; deg2 += m2[j]; \
        } \
        *(s16x8*)(amb + (BUF) * 16384 + swoff) = w1v; \
        *(s16x8*)(amb + (BUF) * 16384 + 8192 + swoff) = w2v; \
    } while (0)

#define K2_COMPUTE(S) do { \
        const int jc = ks * 16 + (S) * 4 + (kg >> 1), cph = kg & 1; \
        s16x8 ha1[4], ha2[4]; \
        _Pragma("unroll") \
        for (int ng = 0; ng < 4; ++ng) { \
            const size_t u1 = (((size_t)ng) * 64 + jc) * 2 + cph; \
            const size_t u2 = (((size_t)(4 + ng)) * 64 + jc) * 2 + cph; \
            ha1[ng] = *(const s16x8*)&hfrag[u1 * 512 + lane * 8]; \
            ha2[ng] = *(const s16x8*)&hfrag[u2 * 512 + lane * 8]; \
        } \
        s16x8 bfa = *(const s16x8*)(amb + ((S) & 1) * 16384 + rdoff); \
        s16x8 bfb = *(const s16x8*)(amb + ((S) & 1) * 16384 + 8192 + rdoff); \
        _Pragma("unroll") \
        for (int ng = 0; ng < 4; ++ng) { \
            acc1[ng] = __builtin_amdgcn_mfma_f32_16x16x32_bf16(ha1[ng], bfa, acc1[ng], 0, 0, 0); \
            acc2[ng] = __builtin_amdgcn_mfma_f32_16x16x32_bf16(ha2[ng], bfb, acc2[ng], 0, 0, 0); \
        } \
    } while (0)

    K2_ISSUE(0);
    K2_CONVSTORE(0);
    __syncthreads();
#pragma unroll
    for (int s = 0; s < 4; ++s) {
        if (s < 3) K2_ISSUE(s + 1);          // issue next slab's HBM loads early (T14 split)
        K2_COMPUTE(s);                        // ds_read frags + hfrag(L2) + 8 MFMA
        if (s < 3) K2_CONVSTORE((s + 1) & 1); // wait own loads, convert, swizzled ds_write
        __syncthreads();
    }

    // ---- epilogue (identical reduction/layout to the passing r1 version) ----
    degp[0][srow][scg] = (float)deg1;
    degp[1][srow][scg] = (float)deg2;
#pragma unroll
    for (int ng = 0; ng < 4; ++ng)
#pragma unroll
        for (int r = 0; r < 4; ++r) accs[kg][ng][lane][r] = acc1[ng][r];
    __syncthreads();
    if (t < 32) {                                   // deg partial for this ks
        const int gg = t >> 4, row = t & 15;
        float s = 0.f;
#pragma unroll
        for (int c2 = 0; c2 < 32; ++c2) s += degp[gg][row][c2];
        pdeg[(size_t)(gg * 4 + ks) * 4096 + i0 + row] = s;
    }

    {   // graph 1 partial: lane holds (n = ng*16+q*4+r, i = i0+l15)
        const int ng = kg & 3, rh = kg >> 2;
        const int i = i0 + l15;
#pragma unroll
        for (int rr = 0; rr < 2; ++rr) {
            const int r = rh * 2 + rr;
            float s = 0.f;
#pragma unroll
            for (int k8 = 0; k8 < 8; ++k8) s += accs[k8][ng][lane][r];
            const int n = ng * 16 + q * 4 + r;
            pagg[(((size_t)ks * 4096 + i) << 6) + n] = s;
        }
    }
    __syncthreads();                                // done reading accs (graph1)
#pragma unroll
    for (int ng = 0; ng < 4; ++ng)
#pragma unroll
        for (int r = 0; r < 4; ++r) accs[kg][ng][lane][r] = acc2[ng][r];
    __syncthreads();
    {   // graph 2 partial
        const int ng = kg & 3, rh = kg >> 2;
        const int i = i0 + l15;
#pragma unroll
        for (int rr = 0; rr < 2; ++rr) {
            const int r = rh * 2 + rr;
            float s = 0.f;
#pragma unroll
            for (int k8 = 0; k8 < 8; ++k8) s += accs[k8][ng][lane][r];
            const int n = ng * 16 + q * 4 + r;
            pagg[(((size_t)(4 + ks) * 4096 + i) << 6) + n] = s;
        }
    }
#undef K2_ISSUE
#undef K2_CONVSTORE
#undef K2_COMPUTE
}

// ---------------- k2b: reduce 4 K-partials, scale by W00/deg, residual, zero-mask -------------
__global__ __launch_bounds__(256) void k2b(const float* __restrict__ pagg, const float* __restrict__ pdeg,
                                           const float* __restrict__ hf, const float* __restrict__ Wp,
                                           float* __restrict__ outv) {
    const int idx = blockIdx.x * 256 + threadIdx.x;  // 0..131071 (quads of n)
    const int gi  = idx >> 4;                        // 0..8191 (g*4096 + i)
    const int nq  = idx & 15;
    const int g   = gi >> 12, i = gi & 4095;
    const float W00 = Wp[0];

    float dg = 0.f;
#pragma unroll
    for (int ks = 0; ks < 4; ++ks) dg += pdeg[(size_t)(g * 4 + ks) * 4096 + i];

    f32x4 s = (f32x4){0.f, 0.f, 0.f, 0.f};
#pragma unroll
    for (int ks = 0; ks < 4; ++ks) {
        const f32x4 p = *(const f32x4*)&pagg[(((size_t)(g * 4 + ks) * 4096 + i) << 6) + nq * 4];
        s += p;
    }
    const f32x4 hv = *(const f32x4*)&hf[((size_t)gi << 6) + nq * 4];
    const float dmax = fmaxf(dg, 1.f);
    f32x4 o;
#pragma unroll
    for (int j = 0; j < 4; ++j)
        o[j] = (dg != 0.f) ? (s[j] * W00 / dmax + hv[j]) : 0.f;
    *(f32x4*)&outv[((size_t)gi << 6) + nq * 4] = o;
}

// ---------------- k3a/k3b: out = feat @ clf_w.T + clf_b (two-stage deterministic reduction) ----------------
__global__ __launch_bounds__(256) void k3a(const float* __restrict__ feat, const float* __restrict__ clfw,
                                           float* __restrict__ part) {
    const int t = threadIdx.x;
    const size_t idx = (size_t)blockIdx.x * 2048 + (size_t)t * 8;
    float4 a0 = *(const float4*)&feat[idx];
    float4 a1 = *(const float4*)&feat[idx + 4];
    float4 c0 = *(const float4*)&clfw[idx];
    float4 c1 = *(const float4*)&clfw[idx + 4];
    float4 d0 = *(const float4*)&clfw[524288 + idx];
    float4 d1 = *(const float4*)&clfw[524288 + idx + 4];
    float s0 = a0.x * c0.x + a0.y * c0.y + a0.z * c0.z + a0.w * c0.w
             + a1.x * c1.x + a1.y * c1.y + a1.z * c1.z + a1.w * c1.w;
    float s1 = a0.x * d0.x + a0.y * d0.y + a0.z * d0.z + a0.w * d0.w
             + a1.x * d1.x + a1.y * d1.y + a1.z * d1.z + a1.w * d1.w;
    __shared__ float r0[256], r1[256];
    r0[t] = s0; r1[t] = s1;
    __syncthreads();
    for (int s = 128; s > 0; s >>= 1) {
        if (t < s) { r0[t] += r0[t + s]; r1[t] += r1[t + s]; }
        __syncthreads();
    }
    if (t == 0) { part[blockIdx.x * 2] = r0[0]; part[blockIdx.x * 2 + 1] = r1[0]; }
}

__global__ void k3b(const float* __restrict__ part, const float* __restrict__ clfb,
                    float* __restrict__ outp) {
    const int t = threadIdx.x;
    __shared__ float r0[256], r1[256];
    r0[t] = part[t * 2]; r1[t] = part[t * 2 + 1];
    __syncthreads();
    for (int s = 128; s > 0; s >>= 1) {
        if (t < s) { r0[t] += r0[t + s]; r1[t] += r1[t + s]; }
        __syncthreads();
    }
    if (t == 0) { outp[0] = r0[0] + clfb[0]; outp[1] = r1[0] + clfb[1]; }
}

extern "C" void kernel_launch(void* const* d_in, const int* in_sizes, int n_in,
                              void* d_out, int out_size, void* d_ws, size_t ws_size,
                              hipStream_t stream) {
    const float* x1   = (const float*)d_in[0];
    const float* x2   = (const float*)d_in[1];
    const int*   adj1 = (const int*)d_in[2];
    const int*   adj2 = (const int*)d_in[3];
    const float* e1w1 = (const float*)d_in[4];
    const float* e1b1 = (const float*)d_in[5];
    const float* e1w2 = (const float*)d_in[6];
    const float* e1b2 = (const float*)d_in[7];
    const float* e1w3 = (const float*)d_in[8];
    const float* e1b3 = (const float*)d_in[9];
    const float* e2w1 = (const float*)d_in[10];
    const float* e2b1 = (const float*)d_in[11];
    const float* e2w2 = (const float*)d_in[12];
    const float* e2b2 = (const float*)d_in[13];
    const float* e2w3 = (const float*)d_in[14];
    const float* e2b3 = (const float*)d_in[15];
    const float* Wp   = (const float*)d_in[16];
    const float* alph = (const float*)d_in[17];
    const float* clfw = (const float*)d_in[18];
    const float* clfb = (const float*)d_in[19];

    char* wsb = (char*)d_ws;
    // Wfrag (2 MB) lives through k1; newv (2 MB) aliases it from k2b on.
    // ph (8 MB, k1 partials) aliases the pagg region: k1b consumes ph before k2 writes pagg.
    unsigned short* Wfrag = (unsigned short*)(wsb);                      // 2 MB
    float* newv = (float*)(wsb);                                         // 2 MB (aliases Wfrag)
    unsigned short* hfrag = (unsigned short*)(wsb + (2u << 20));         // 1 MB
    float* hf   = (float*)(wsb + (3u << 20));                            // 2 MB
    float* T    = (float*)(wsb + (5u << 20));                            // 128 KB
    float* beff = (float*)(wsb + (5u << 20) + (1u << 17));               // 512 B
    float* part = (float*)(wsb + (5u << 20) + (1u << 17) + 4096);        // 2 KB
    float* pagg = (float*)(wsb + (6u << 20));                            // 8 MB [2][4][4096][64]
    float* ph   = (float*)(wsb + (6u << 20));                            // 8 MB [4][8192][64] (aliases pagg)
    float* pdeg = (float*)(wsb + (14u << 20));                           // 128 KB [2][4][4096]

    hipLaunchKernelGGL(k0a, dim3(64), dim3(256), 0, stream,
                       e1w2, e1w3, e1b1, e1b2, e1b3, e2w2, e2w3, e2b1, e2b2, e2b3, T, beff);
    hipLaunchKernelGGL(k0b, dim3(512), dim3(256), 0, stream, e1w1, e2w1, T, Wfrag);
    hipLaunchKernelGGL(k1, dim3(512), dim3(512), 0, stream, x1, x2, Wfrag, ph);
    hipLaunchKernelGGL(k1b, dim3(512), dim3(256), 0, stream, ph, beff, hf, hfrag);
    hipLaunchKernelGGL(k2, dim3(1024), dim3(512), 0, stream, adj1, adj2, alph, hfrag, pagg, pdeg);
    hipLaunchKernelGGL(k2b, dim3(512), dim3(256), 0, stream, pagg, pdeg, hf, Wp, newv);
    hipLaunchKernelGGL(k3a, dim3(256), dim3(256), 0, stream, newv, clfw, part);
    hipLaunchKernelGGL(k3b, dim3(1), dim3(256), 0, stream, part, clfb, (float*)d_out);
}